// Round 1
// baseline (181.111 us; speedup 1.0000x reference)
//
#include <hip/hip_runtime.h>
#include <math.h>

#define BATCH 16
#define OC_TOT 512
#define HH 128
#define WW 128
#define KK 5
#define ROUT_ 16
#define NOC 32      // output channels per block
#define ROWS 8      // output rows per block
#define NTHREADS 256

__global__ __launch_bounds__(NTHREADS, 4)
void groupconv_kernel(const float* __restrict__ x,
                      const float* __restrict__ weight,
                      const float* __restrict__ bias,
                      float* __restrict__ out)
{
    __shared__ float sIn[ROWS + 4][WW + 4];   // 12 x 132 input tile (zero-padded halo)
    __shared__ float sW[NOC][26];             // 25 rotated taps + bias per local oc

    const int tid = threadIdx.x;
    const int bid = blockIdx.x;
    // grid = BATCH * (HH/ROWS) * (OC_TOT/NOC) = 16*16*16 = 4096
    const int octile = bid & 15;
    const int htile  = (bid >> 4) & 15;
    const int b      = bid >> 8;
    const int h0     = htile * ROWS;
    const int ocbase = octile * NOC;

    // ---- stage input tile (with zero halo) ----
    const float* xb = x + b * (HH * WW);
    for (int idx = tid; idx < (ROWS + 4) * (WW + 4); idx += NTHREADS) {
        int ry = idx / (WW + 4);
        int cx = idx - ry * (WW + 4);
        int gy = h0 - 2 + ry;
        int gx = cx - 2;
        float v = 0.0f;
        if (gy >= 0 && gy < HH && gx >= 0 && gx < WW)
            v = xb[gy * WW + gx];
        sIn[ry][cx] = v;
    }

    // ---- compute rotated filter taps for this block's 32 ocs ----
    for (int idx = tid; idx < NOC * 25; idx += NTHREADS) {
        int i   = idx / 25;            // local oc
        int t25 = idx - i * 25;
        int ky  = t25 / 5;
        int kx  = t25 - ky * 5;
        int oc  = ocbase + i;
        int o   = oc >> 4;             // / ROUT
        int r   = oc & 15;
        const float* wp = weight + o * 25;   // weight is (32,1,1,5,5); d=1 -> plane 0 exactly
        float theta = 0.39269908169872414f * (float)r;   // 2*pi/16 * r
        float cth = cosf(theta), sth = sinf(theta);
        float ty = ((float)ky + 0.5f) * (2.0f / (float)KK) - 1.0f;
        float tx = ((float)kx + 0.5f) * (2.0f / (float)KK) - 1.0f;
        float xi =  cth * tx + sth * ty;
        float yi = -sth * tx + cth * ty;
        float px = (xi + 1.0f) * ((float)KK * 0.5f) - 0.5f;
        float py = (yi + 1.0f) * ((float)KK * 0.5f) - 0.5f;
        float fx0 = floorf(px), fy0 = floorf(py);
        int   x0 = (int)fx0,  y0 = (int)fy0;
        float wx = px - fx0,  wy = py - fy0;
        float v00 = (y0 >= 0   && y0 < KK   && x0 >= 0   && x0 < KK  ) ? wp[y0* KK + x0]           : 0.0f;
        float v01 = (y0 >= 0   && y0 < KK   && x0+1 >= 0 && x0+1 < KK) ? wp[y0 * KK + x0 + 1]       : 0.0f;
        float v10 = (y0+1 >= 0 && y0+1 < KK && x0 >= 0   && x0 < KK  ) ? wp[(y0+1) * KK + x0]       : 0.0f;
        float v11 = (y0+1 >= 0 && y0+1 < KK && x0+1 >= 0 && x0+1 < KK) ? wp[(y0+1) * KK + x0 + 1]   : 0.0f;
        float val = v00 * (1.0f - wy) * (1.0f - wx)
                  + v01 * (1.0f - wy) * wx
                  + v10 * wy * (1.0f - wx)
                  + v11 * wy * wx;
        sW[i][t25] = val;
    }
    for (int i = tid; i < NOC; i += NTHREADS) {
        sW[i][25] = bias[(ocbase + i) >> 4];
    }
    __syncthreads();

    // ---- compute: each thread owns 4 consecutive output cols x 1 row, all 32 ocs ----
    const int row  = tid >> 5;          // 0..7
    const int wcol = (tid & 31) * 4;    // 0,4,...,124
    const int h    = h0 + row;

    // 5x8 input window in registers (read LDS once; statically indexed)
    float win[5][8];
#pragma unroll
    for (int r5 = 0; r5 < 5; ++r5) {
        float4 a = *(const float4*)&sIn[row + r5][wcol];
        float4 c = *(const float4*)&sIn[row + r5][wcol + 4];
        win[r5][0] = a.x; win[r5][1] = a.y; win[r5][2] = a.z; win[r5][3] = a.w;
        win[r5][4] = c.x; win[r5][5] = c.y; win[r5][6] = c.z; win[r5][7] = c.w;
    }

    float* outb = out + ((size_t)b * OC_TOT + ocbase) * (size_t)(HH * WW)
                      + (size_t)h * WW + wcol;
    for (int i = 0; i < NOC; ++i) {
        float bz = sW[i][25];
        float acc0 = bz, acc1 = bz, acc2 = bz, acc3 = bz;
#pragma unroll
        for (int ky = 0; ky < 5; ++ky) {
#pragma unroll
            for (int kx = 0; kx < 5; ++kx) {
                float wv = sW[i][ky * 5 + kx];
                acc0 = fmaf(win[ky][kx],     wv, acc0);
                acc1 = fmaf(win[ky][kx + 1], wv, acc1);
                acc2 = fmaf(win[ky][kx + 2], wv, acc2);
                acc3 = fmaf(win[ky][kx + 3], wv, acc3);
            }
        }
        float4 o4 = make_float4(acc0, acc1, acc2, acc3);
        *(float4*)(outb + (size_t)i * (HH * WW)) = o4;
    }
}

extern "C" void kernel_launch(void* const* d_in, const int* in_sizes, int n_in,
                              void* d_out, int out_size, void* d_ws, size_t ws_size,
                              hipStream_t stream)
{
    const float* x      = (const float*)d_in[0];  // (16,1,128,128)
    const float* weight = (const float*)d_in[1];  // (32,1,1,5,5)
    const float* bias   = (const float*)d_in[2];  // (32,)
    float* out = (float*)d_out;                   // (16,32,16,128,128)

    const int nblocks = BATCH * (HH / ROWS) * (OC_TOT / NOC);  // 4096
    groupconv_kernel<<<nblocks, NTHREADS, 0, stream>>>(x, weight, bias, out);
}

// Round 2
// 134.192 us; speedup vs baseline: 1.3496x; 1.3496x over previous
//
#include <hip/hip_runtime.h>
#include <math.h>

#define BATCH 16
#define OC_TOT 512
#define HH 128
#define WW 128
#define KK 5
#define NOC 32      // output channels per block
#define ROWS 16     // output rows per block
#define NTHREADS 256
#define HW (HH * WW)

// Each block: (batch b, 16-row tile, 32 output channels).
// Thread: 1 row x 8 consecutive cols, all 32 ocs.
// Weights (25 rotated taps + bias) packed 28 floats/oc in LDS, read as float4
// broadcasts (uniform addr, conflict-free); input window held in registers.
__global__ __launch_bounds__(NTHREADS, 2)
void groupconv_kernel(const float* __restrict__ x,
                      const float* __restrict__ weight,
                      const float* __restrict__ bias,
                      float* __restrict__ out)
{
    __shared__ float sIn[ROWS + 4][WW + 4];   // 20 x 132 input tile (zero halo)
    __shared__ float sW[NOC][28];             // 25 taps + bias + pad (112 B rows, 16B-aligned)

    const int tid = threadIdx.x;
    const int bid = blockIdx.x;
    // grid = BATCH * (HH/ROWS) * (OC_TOT/NOC) = 16*8*16 = 2048
    const int octile = bid & 15;
    const int htile  = (bid >> 4) & 7;
    const int b      = bid >> 7;
    const int h0     = htile * ROWS;
    const int ocbase = octile * NOC;

    // ---- stage input tile (with zero halo) ----
    const float* xb = x + b * HW;
    for (int idx = tid; idx < (ROWS + 4) * (WW + 4); idx += NTHREADS) {
        int ry = idx / (WW + 4);
        int cx = idx - ry * (WW + 4);
        int gy = h0 - 2 + ry;
        int gx = cx - 2;
        float v = 0.0f;
        if (gy >= 0 && gy < HH && gx >= 0 && gx < WW)
            v = xb[gy * WW + gx];
        sIn[ry][cx] = v;
    }

    // ---- compute rotated filter taps (d=1 -> z-interp picks plane 0 exactly) ----
    for (int idx = tid; idx < NOC * 25; idx += NTHREADS) {
        int i   = idx / 25;            // local oc
        int t25 = idx - i * 25;
        int ky  = t25 / 5;
        int kx  = t25 - ky * 5;
        int oc  = ocbase + i;
        int o   = oc >> 4;
        int r   = oc & 15;
        const float* wp = weight + o * 25;
        float theta = 0.39269908169872414f * (float)r;   // 2*pi/16 * r
        float cth = cosf(theta), sth = sinf(theta);
        float ty = ((float)ky + 0.5f) * (2.0f / (float)KK) - 1.0f;
        float tx = ((float)kx + 0.5f) * (2.0f / (float)KK) - 1.0f;
        float xi =  cth * tx + sth * ty;
        float yi = -sth * tx + cth * ty;
        float px = (xi + 1.0f) * ((float)KK * 0.5f) - 0.5f;
        float py = (yi + 1.0f) * ((float)KK * 0.5f) - 0.5f;
        float fx0 = floorf(px), fy0 = floorf(py);
        int   x0 = (int)fx0,  y0 = (int)fy0;
        float wx = px - fx0,  wy = py - fy0;
        float v00 = (y0 >= 0   && y0 < KK   && x0 >= 0   && x0 < KK  ) ? wp[y0 * KK + x0]         : 0.0f;
        float v01 = (y0 >= 0   && y0 < KK   && x0+1 >= 0 && x0+1 < KK) ? wp[y0 * KK + x0 + 1]     : 0.0f;
        float v10 = (y0+1 >= 0 && y0+1 < KK && x0 >= 0   && x0 < KK  ) ? wp[(y0+1) * KK + x0]     : 0.0f;
        float v11 = (y0+1 >= 0 && y0+1 < KK && x0+1 >= 0 && x0+1 < KK) ? wp[(y0+1) * KK + x0 + 1] : 0.0f;
        float val = v00 * (1.0f - wy) * (1.0f - wx)
                  + v01 * (1.0f - wy) * wx
                  + v10 * wy * (1.0f - wx)
                  + v11 * wy * wx;
        sW[i][t25] = val;
    }
    for (int i = tid; i < NOC * 3; i += NTHREADS) {      // bias + zero the 2 pad slots
        int oc = i / 3, slot = 25 + (i - oc * 3);
        sW[oc][slot] = (slot == 25) ? bias[(ocbase + oc) >> 4] : 0.0f;
    }
    __syncthreads();

    // ---- compute: each thread = 1 row x 8 cols, loop 32 ocs ----
    const int row  = tid >> 4;          // 0..15
    const int wcol = (tid & 15) * 8;    // 0,8,...,120
    const int h    = h0 + row;

    // 5x12 input window in registers (15 ds_read_b128, one-time)
    float win[5][12];
#pragma unroll
    for (int r5 = 0; r5 < 5; ++r5) {
        float4 a = *(const float4*)&sIn[row + r5][wcol];
        float4 c = *(const float4*)&sIn[row + r5][wcol + 4];
        float4 e = *(const float4*)&sIn[row + r5][wcol + 8];
        win[r5][0] = a.x; win[r5][1]  = a.y; win[r5][2]  = a.z; win[r5][3]  = a.w;
        win[r5][4] = c.x; win[r5][5]  = c.y; win[r5][6]  = c.z; win[r5][7]  = c.w;
        win[r5][8] = e.x; win[r5][9]  = e.y; win[r5][10] = e.z; win[r5][11] = e.w;
    }

    float* op = out + ((size_t)b * OC_TOT + ocbase) * (size_t)HW
                    + (size_t)h * WW + wcol;
    for (int i = 0; i < NOC; ++i) {
        const float4* wrow = (const float4*)&sW[i][0];
        float tap[28];
        *(float4*)&tap[0]  = wrow[0];
        *(float4*)&tap[4]  = wrow[1];
        *(float4*)&tap[8]  = wrow[2];
        *(float4*)&tap[12] = wrow[3];
        *(float4*)&tap[16] = wrow[4];
        *(float4*)&tap[20] = wrow[5];
        *(float4*)&tap[24] = wrow[6];
        float bz = tap[25];
        float a0 = bz, a1 = bz, a2 = bz, a3 = bz, a4 = bz, a5 = bz, a6 = bz, a7 = bz;
#pragma unroll
        for (int ky = 0; ky < 5; ++ky) {
#pragma unroll
            for (int kx = 0; kx < 5; ++kx) {
                float wv = tap[ky * 5 + kx];
                a0 = fmaf(win[ky][kx],     wv, a0);
                a1 = fmaf(win[ky][kx + 1], wv, a1);
                a2 = fmaf(win[ky][kx + 2], wv, a2);
                a3 = fmaf(win[ky][kx + 3], wv, a3);
                a4 = fmaf(win[ky][kx + 4], wv, a4);
                a5 = fmaf(win[ky][kx + 5], wv, a5);
                a6 = fmaf(win[ky][kx + 6], wv, a6);
                a7 = fmaf(win[ky][kx + 7], wv, a7);
            }
        }
        *(float4*)op       = make_float4(a0, a1, a2, a3);
        *(float4*)(op + 4) = make_float4(a4, a5, a6, a7);
        op += HW;
    }
}

extern "C" void kernel_launch(void* const* d_in, const int* in_sizes, int n_in,
                              void* d_out, int out_size, void* d_ws, size_t ws_size,
                              hipStream_t stream)
{
    const float* x      = (const float*)d_in[0];  // (16,1,128,128)
    const float* weight = (const float*)d_in[1];  // (32,1,1,5,5)
    const float* bias   = (const float*)d_in[2];  // (32,)
    float* out = (float*)d_out;                   // (16,32,16,128,128)

    const int nblocks = BATCH * (HH / ROWS) * (OC_TOT / NOC);  // 2048
    groupconv_kernel<<<nblocks, NTHREADS, 0, stream>>>(x, weight, bias, out);
}